// Round 14
// baseline (248.523 us; speedup 1.0000x reference)
//
#include <hip/hip_runtime.h>
#include <stdint.h>

#define DMODEL 1024
#define NHEAD 16
#define DH 64
#define BB 4
#define SS 2048
#define MROWS (BB * SS)   // 8192

typedef __bf16 bfx8 __attribute__((ext_vector_type(8)));
typedef float f32x4 __attribute__((ext_vector_type(4)));
typedef float fvec4 __attribute__((ext_vector_type(4)));
typedef int i32x4 __attribute__((ext_vector_type(4)));
typedef unsigned short u16x8 __attribute__((ext_vector_type(8)));
typedef unsigned short u16x4 __attribute__((ext_vector_type(4)));

__device__ __forceinline__ unsigned short f2bf(float f) {
    union { float f; unsigned int u; } v; v.f = f;
    unsigned int r = v.u + 0x7FFFu + ((v.u >> 16) & 1u);
    return (unsigned short)(r >> 16);
}

// packed fp32x2 -> bf16x2 (RNE), single HW instruction
__device__ __forceinline__ unsigned int cvtpk(float lo, float hi) {
    unsigned int r;
    asm("v_cvt_pk_bf16_f32 %0, %1, %2" : "=v"(r) : "v"(lo), "v"(hi));
    return r;
}

// async global->LDS, 16B per lane. LDS dest must be linear: wave base + lane*16.
typedef __attribute__((address_space(1))) const void gas_t;
typedef __attribute__((address_space(3))) void las_t;
__device__ __forceinline__ void gload_lds16(const void* g, void* l) {
    __builtin_amdgcn_global_load_lds((gas_t*)g, (las_t*)l, 16, 0, 0);
}

// K-row permutation for swapped-QK in-register P trick.
// i bits [nf1 nf0 lg1 lg0 r1 r0] -> sigma bits [nf1 lg1 lg0 nf0 r1 r0]
__device__ __forceinline__ int sigma_k(int i) {
    return (i & 0x20) | ((i & 0x0C) << 1) | ((i & 0x10) >> 2) | (i & 3);
}

// ---------------------------------------------------------------------------
// fp32 -> bf16 convert for q,k,v in one launch (blockIdx.y selects tensor)
// ---------------------------------------------------------------------------
__global__ void cvt3_kernel(const float* __restrict__ s0, const float* __restrict__ s1,
                            const float* __restrict__ s2,
                            unsigned short* __restrict__ d0, unsigned short* __restrict__ d1,
                            unsigned short* __restrict__ d2, int n8)
{
    const float* s = (blockIdx.y == 0) ? s0 : (blockIdx.y == 1) ? s1 : s2;
    unsigned short* d = (blockIdx.y == 0) ? d0 : (blockIdx.y == 1) ? d1 : d2;
    int i = blockIdx.x * blockDim.x + threadIdx.x;
    if (i >= n8) return;
    fvec4 a = *reinterpret_cast<const fvec4*>(&s[(size_t)i * 8]);
    fvec4 b = *reinterpret_cast<const fvec4*>(&s[(size_t)i * 8 + 4]);
    u16x8 o;
    #pragma unroll
    for (int j = 0; j < 4; ++j) { o[j] = f2bf(a[j]); o[j + 4] = f2bf(b[j]); }
    *reinterpret_cast<u16x8*>(&d[(size_t)i * 8]) = o;
}

// ---------------------------------------------------------------------------
// Transpose + convert: Wt[n][k] (bf16) = W[k][n] (fp32). 64x64 tiles.
// blockIdx.z selects which weight.
// ---------------------------------------------------------------------------
__global__ void transpose_cvt3_kernel(const float* __restrict__ W0, unsigned short* __restrict__ T0,
                                      const float* __restrict__ W1, unsigned short* __restrict__ T1,
                                      const float* __restrict__ W2, unsigned short* __restrict__ T2)
{
    const float* W = (blockIdx.z == 0) ? W0 : (blockIdx.z == 1) ? W1 : W2;
    unsigned short* Wt = (blockIdx.z == 0) ? T0 : (blockIdx.z == 1) ? T1 : T2;
    __shared__ unsigned short t[64][72];
    const int tid = threadIdx.x;
    const int r0 = blockIdx.y * 64, c0 = blockIdx.x * 64;
    #pragma unroll
    for (int i = 0; i < 4; ++i) {
        int idx = tid + i * 256;
        int r = idx >> 4, c4 = idx & 15;
        fvec4 v = *reinterpret_cast<const fvec4*>(&W[(size_t)(r0 + r) * DMODEL + c0 + c4 * 4]);
        #pragma unroll
        for (int j = 0; j < 4; ++j) t[c4 * 4 + j][r] = f2bf(v[j]);
    }
    __syncthreads();
    #pragma unroll
    for (int i = 0; i < 2; ++i) {
        int idx = tid + i * 256;
        int r = idx >> 3, c8 = idx & 7;
        u16x8 v = *reinterpret_cast<const u16x8*>(&t[r][c8 * 8]);
        *reinterpret_cast<u16x8*>(&Wt[(size_t)(c0 + r) * DMODEL + r0 + c8 * 8]) = v;
    }
}

// ---------------------------------------------------------------------------
// GEMM: out = A @ Bt^T + bias; bf16 in via global_load_lds.
// TM x 128 tile (TM = 128 or 64), BK=64, 4 waves, per-kk fragment loads,
// __launch_bounds__(256,4). TM=64 doubles the grid -> 4 blocks/CU for
// single-GEMM launches. blockIdx.z picks arg set.
// mode: 0 = bf16 row-major out, 2 = fp32 row-major out,
//       3 = bf16 Vt-layout out: O[((b*16+h)*64+d)*2048 + s] (per-head V^T)
// ---------------------------------------------------------------------------
struct GArg {
    const unsigned short* A;
    const unsigned short* Bt;
    const float* bias;
    void* O;
    float osc;
    int mode;
};

template<int TM>
__global__ __launch_bounds__(256, 4)
void gemm_kernel(GArg g0, GArg g1, int M, int N, int K)
{
    constexpr int MF = TM / 32;                  // m-fragments per wave
    const GArg g = blockIdx.z ? g1 : g0;
    __shared__ unsigned short sA[TM * 64];
    __shared__ unsigned short sB[128 * 64];
    const int tid  = threadIdx.x;
    const int lane = tid & 63;
    const int wave = tid >> 6;
    const int wm = (wave >> 1) * (TM / 2), wn = (wave & 1) * 64;
    const int m0 = blockIdx.x * TM, n0 = blockIdx.y * 128;
    const int lr = lane & 15;
    const int lg = lane >> 4;

    f32x4 acc[MF][4] = {};

    for (int kk0 = 0; kk0 < K; kk0 += 64) {
        __syncthreads();
        #pragma unroll
        for (int i = 0; i < TM / 32; ++i) {
            int c = tid + i * 256;
            int row = c >> 3, col8 = c & 7;
            gload_lds16(&g.A[(size_t)(m0 + row) * K + kk0 + col8 * 8], &sA[c * 8]);
        }
        #pragma unroll
        for (int i = 0; i < 4; ++i) {
            int c = tid + i * 256;
            int row = c >> 3, col8 = c & 7;
            gload_lds16(&g.Bt[(size_t)(n0 + row) * K + kk0 + col8 * 8], &sB[c * 8]);
        }
        __syncthreads();

        #pragma unroll
        for (int kk = 0; kk < 2; ++kk) {
            bfx8 af[MF], bfr[4];
            #pragma unroll
            for (int m = 0; m < MF; ++m)
                af[m] = *reinterpret_cast<const bfx8*>(
                    &sA[(wm + m * 16 + lr) * 64 + kk * 32 + lg * 8]);
            #pragma unroll
            for (int n = 0; n < 4; ++n)
                bfr[n] = *reinterpret_cast<const bfx8*>(
                    &sB[(wn + n * 16 + lr) * 64 + kk * 32 + lg * 8]);
            #pragma unroll
            for (int m = 0; m < MF; ++m)
                #pragma unroll
                for (int n = 0; n < 4; ++n)
                    acc[m][n] = __builtin_amdgcn_mfma_f32_16x16x32_bf16(
                        af[m], bfr[n], acc[m][n], 0, 0, 0);
        }
    }

    #pragma unroll
    for (int n = 0; n < 4; ++n) {
        int col = n0 + wn + n * 16 + lr;
        float bv = g.bias[col];
        #pragma unroll
        for (int m = 0; m < MF; ++m) {
            int rowb = m0 + wm + m * 16 + lg * 4;
            float val[4];
            #pragma unroll
            for (int r = 0; r < 4; ++r) val[r] = (acc[m][n][r] + bv) * g.osc;
            if (g.mode == 0) {
                #pragma unroll
                for (int r = 0; r < 4; ++r)
                    ((unsigned short*)g.O)[(size_t)(rowb + r) * N + col] = f2bf(val[r]);
            } else if (g.mode == 2) {
                #pragma unroll
                for (int r = 0; r < 4; ++r)
                    ((float*)g.O)[(size_t)(rowb + r) * N + col] = val[r];
            } else {
                // Vt layout: rows rowb..rowb+3 are consecutive s in one batch
                int bq = rowb >> 11, s = rowb & 2047;
                int hh = col >> 6, d = col & 63;
                u16x4 pk;
                #pragma unroll
                for (int r = 0; r < 4; ++r) pk[r] = f2bf(val[r]);
                size_t idx = ((size_t)(bq * 16 + hh) * 64 + d) * 2048 + s;
                *reinterpret_cast<u16x4*>(&((unsigned short*)g.O)[idx]) = pk;
            }
        }
    }
}

// ---------------------------------------------------------------------------
// Flash-style causal attention, merged q-tile pair, single k-walk.
// 8-wave (512-thr) blocks; wave owns 16 q-rows of EACH of the two q-tiles
// {15-p, p}; one walk over k-tiles 0..2*(15-p)+1 serves both states (state B
// active while k0 <= its causal limit). Staging pairs 17 -> avg 12.5.
// l via ones-MFMA (C-layout, shuffle-free epilogue); max3 pmax tree;
// swizzled conflict-free LDS; sigma-permuted K rows; in-register P.
// Q pre-scaled by 1/sqrt(2048)*log2(e). Q,K: [B*S][H*DH]; Vt: [B*H][DH][S].
// ---------------------------------------------------------------------------
__global__ __launch_bounds__(512, 4)
void attn_kernel(const unsigned short* __restrict__ Q,
                 const unsigned short* __restrict__ K,
                 const unsigned short* __restrict__ Vt,
                 unsigned short* __restrict__ C)
{
    __shared__ unsigned short sK[2 * 4096];      // 2 tiles; row i = K k0+sigma(i)
    __shared__ unsigned short sV[2 * 4096];      // 2 tiles; row d, cols k

    const int tid  = threadIdx.x;                // 0..511
    const int lane = tid & 63;
    const int wave = tid >> 6;                   // 0..7
    const int lr = lane & 15, lg = lane >> 4;
    const int bh = blockIdx.x;
    const int p  = blockIdx.y;                   // pair index 0..7
    const int qtA = 15 - p, qtB = p;
    const int q0A = qtA * 128, q0B = qtB * 128;
    const int b = bh >> 4, h = bh & 15;
    const size_t rowbase = (size_t)b * SS;
    const int hcol = h * DH;

    // staging coords: one 8-elem chunk per thread (64 rows x 8 chunks = 512)
    const int srow = tid >> 3, sc8 = tid & 7;
    const int sig  = sigma_k(srow);
    const int woff = srow * 64 + ((sc8 ^ (srow & 7)) * 8);
    const int p0 = lg ^ (lr & 7);                // swizzled chunk for QK reads

    const u16x8 onesu = {0x3F80, 0x3F80, 0x3F80, 0x3F80, 0x3F80, 0x3F80, 0x3F80, 0x3F80};
    union { u16x8 u; bfx8 b; } onesc; onesc.u = onesu;
    const bfx8 ones = onesc.b;

    // Q fragments for both states
    bfx8 aqA[2], aqB[2];
    {
        int qrA = q0A + wave * 16 + lr;
        const unsigned short* qp = &Q[(rowbase + qrA) * DMODEL + hcol + lg * 8];
        aqA[0] = *reinterpret_cast<const bfx8*>(qp);
        aqA[1] = *reinterpret_cast<const bfx8*>(qp + 32);
        int qrB = q0B + wave * 16 + lr;
        const unsigned short* qb = &Q[(rowbase + qrB) * DMODEL + hcol + lg * 8];
        aqB[0] = *reinterpret_cast<const bfx8*>(qb);
        aqB[1] = *reinterpret_cast<const bfx8*>(qb + 32);
    }

    float m_runA = 0.f, m_runB = 0.f;
    f32x4 acc_lA = {}, acc_lB = {};
    f32x4 acc_oA[4] = {}, acc_oB[4] = {};
    bool mzA = true, mzB = true;
    const int qmaxA = q0A + wave * 16 + 15;
    const int qmaxB = q0B + wave * 16 + 15;
    const int npairs = qtA + 1;                  // k-tiles = 2*npairs

    // compute one 64-k-tile for one state (R13-verified body)
    auto compute = [&](int k0, int q0, bfx8 (&aq)[2], f32x4 (&acc_o)[4],
                       f32x4& acc_l, float& m_run, bool& mz,
                       const unsigned short* kb, const unsigned short* vb) {
        f32x4 sc[4];
        __builtin_amdgcn_s_setprio(1);
        #pragma unroll
        for (int nf = 0; nf < 4; ++nf) {
            int i = nf * 16 + lr;
            bfx8 ak0 = *reinterpret_cast<const bfx8*>(&kb[i * 64 + p0 * 8]);
            bfx8 ak1 = *reinterpret_cast<const bfx8*>(&kb[i * 64 + (p0 ^ 4) * 8]);
            f32x4 sv = {0.f, 0.f, 0.f, 0.f};
            sv = __builtin_amdgcn_mfma_f32_16x16x32_bf16(ak0, aq[0], sv, 0, 0, 0);
            sv = __builtin_amdgcn_mfma_f32_16x16x32_bf16(ak1, aq[1], sv, 0, 0, 0);
            sc[nf] = sv;
        }
        __builtin_amdgcn_s_setprio(0);
        // causal mask (diagonal-overlapping tiles only)
        if (k0 + 63 > q0 + wave * 16) {
            int qrow = q0 + wave * 16 + lr;
            #pragma unroll
            for (int nf = 0; nf < 4; ++nf) {
                int kb_ = k0 + ((nf >> 1) << 5) + (lg << 3) + ((nf & 1) << 2);
                #pragma unroll
                for (int r = 0; r < 4; ++r)
                    if (kb_ + r > qrow) sc[nf][r] = -3.0e38f;
            }
        }
        // pmax via max3-friendly triples
        float a0 = fmaxf(fmaxf(sc[0][0], sc[0][1]), sc[0][2]);
        float a1 = fmaxf(fmaxf(sc[0][3], sc[1][0]), sc[1][1]);
        float a2 = fmaxf(fmaxf(sc[1][2], sc[1][3]), sc[2][0]);
        float a3 = fmaxf(fmaxf(sc[2][1], sc[2][2]), sc[2][3]);
        float a4 = fmaxf(fmaxf(sc[3][0], sc[3][1]), sc[3][2]);
        float pmax = fmaxf(fmaxf(fmaxf(a0, a1), fmaxf(a2, a3)),
                           fmaxf(a4, sc[3][3]));
        if (mz && __all(pmax <= 8.0f)) {
            #pragma unroll
            for (int nf = 0; nf < 4; ++nf)
                #pragma unroll
                for (int r = 0; r < 4; ++r)
                    sc[nf][r] = __builtin_exp2f(sc[nf][r]);
        } else {
            mz = false;
            float mx = pmax;
            mx = fmaxf(mx, __shfl_xor(mx, 16, 64));
            mx = fmaxf(mx, __shfl_xor(mx, 32, 64));
            float mnew = fmaxf(m_run, mx);
            float fs = __builtin_exp2f(m_run - mnew);
            m_run = mnew;
            #pragma unroll
            for (int nf = 0; nf < 4; ++nf)
                #pragma unroll
                for (int r = 0; r < 4; ++r)
                    sc[nf][r] = __builtin_exp2f(sc[nf][r] - mnew);
            #pragma unroll
            for (int r = 0; r < 4; ++r) {
                float fsa = __shfl(fs, lg * 4 + r, 64);
                #pragma unroll
                for (int d = 0; d < 4; ++d) acc_o[d][r] *= fsa;
                acc_l[r] *= fsa;
            }
        }
        // pack P in-register; PV + l via MFMA
        #pragma unroll
        for (int h2 = 0; h2 < 2; ++h2) {
            union { i32x4 i; bfx8 b; } pa;
            pa.i[0] = cvtpk(sc[2 * h2][0],     sc[2 * h2][1]);
            pa.i[1] = cvtpk(sc[2 * h2][2],     sc[2 * h2][3]);
            pa.i[2] = cvtpk(sc[2 * h2 + 1][0], sc[2 * h2 + 1][1]);
            pa.i[3] = cvtpk(sc[2 * h2 + 1][2], sc[2 * h2 + 1][3]);
            __builtin_amdgcn_s_setprio(1);
            acc_l = __builtin_amdgcn_mfma_f32_16x16x32_bf16(pa.b, ones, acc_l, 0, 0, 0);
            #pragma unroll
            for (int d = 0; d < 4; ++d) {
                int i = d * 16 + lr;
                int pv = ((h2 << 2) | lg) ^ (lr & 7);
                bfx8 bv0 = *reinterpret_cast<const bfx8*>(&vb[i * 64 + pv * 8]);
                acc_o[d] = __builtin_amdgcn_mfma_f32_16x16x32_bf16(pa.b, bv0, acc_o[d], 0, 0, 0);
            }
            __builtin_amdgcn_s_setprio(0);
        }
    };

    // prologue: load pair 0 (tiles 0,1) into regs
    u16x8 rk[2], rv[2];
    #pragma unroll
    for (int s = 0; s < 2; ++s) {
        rk[s] = *reinterpret_cast<const u16x8*>(
            &K[(rowbase + s * 64 + sig) * DMODEL + hcol + sc8 * 8]);
        rv[s] = *reinterpret_cast<const u16x8*>(
            &Vt[((size_t)bh * DH + srow) * SS + s * 64 + sc8 * 8]);
    }

    for (int u = 0; u < npairs; ++u) {
        __syncthreads();                         // previous compute done reading LDS
        #pragma unroll
        for (int s = 0; s < 2; ++s) {
            *reinterpret_cast<u16x8*>(&sK[s * 4096 + woff]) = rk[s];
            *reinterpret_cast<u16x8*>(&sV[s * 4096 + woff]) = rv[s];
        }
        __syncthreads();                         // LDS(pair u) visible
        // issue loads for pair u+1; latency hides under compute
        if (u + 1 < npairs) {
            #pragma unroll
            for (int s = 0; s < 2; ++s) {
                const int kk = (2 * u + 2 + s) * 64;
                rk[s] = *reinterpret_cast<const u16x8*>(
                    &K[(rowbase + kk + sig) * DMODEL + hcol + sc8 * 8]);
                rv[s] = *reinterpret_cast<const u16x8*>(
                    &Vt[((size_t)bh * DH + srow) * SS + kk + sc8 * 8]);
            }
        }
        #pragma unroll
        for (int s = 0; s < 2; ++s) {
            const int k0 = (2 * u + s) * 64;
            const unsigned short* kb = &sK[s * 4096];
            const unsigned short* vb = &sV[s * 4096];
            if (k0 <= qmaxA)
                compute(k0, q0A, aqA, acc_oA, acc_lA, m_runA, mzA, kb, vb);
            if (k0 <= qmaxB)
                compute(k0, q0B, aqB, acc_oB, acc_lB, m_runB, mzB, kb, vb);
        }
    }

    // epilogue: shuffle-free (acc_l shares acc_o's C-layout rows)
    auto epi = [&](int q0, f32x4 (&acc_o)[4], f32x4& acc_l) {
        f32x4 linv;
        #pragma unroll
        for (int r = 0; r < 4; ++r) linv[r] = 1.0f / acc_l[r];
        const int qrb = q0 + wave * 16 + lg * 4;
        #pragma unroll
        for (int d = 0; d < 4; ++d) {
            int col = hcol + d * 16 + lr;
            #pragma unroll
            for (int r = 0; r < 4; ++r)
                C[(rowbase + qrb + r) * DMODEL + col] = f2bf(acc_o[d][r] * linv[r]);
        }
    };
    epi(q0A, acc_oA, acc_lA);
    epi(q0B, acc_oB, acc_lB);
}

// ---------------------------------------------------------------------------
extern "C" void kernel_launch(void* const* d_in, const int* in_sizes, int n_in,
                              void* d_out, int out_size, void* d_ws, size_t ws_size,
                              hipStream_t stream)
{
    const float* q  = (const float*)d_in[0];
    const float* k  = (const float*)d_in[1];
    const float* v  = (const float*)d_in[2];
    const float* Wq = (const float*)d_in[3];
    const float* bq = (const float*)d_in[4];
    const float* Wk = (const float*)d_in[5];
    const float* bk = (const float*)d_in[6];
    const float* Wv = (const float*)d_in[7];
    const float* bv = (const float*)d_in[8];
    const float* Wf = (const float*)d_in[9];
    const float* bf = (const float*)d_in[10];

    unsigned short* ws = (unsigned short*)d_ws;
    const size_t SZ = (size_t)MROWS * DMODEL;        // 8388608 elems
    unsigned short* ws0 = ws;                        // qb16 -> Vt -> (dead)
    unsigned short* ws1 = ws + SZ;                   // kb16 -> Cb
    unsigned short* ws2 = ws + 2 * SZ;               // vb16 -> WfT
    unsigned short* ws3 = ws + 3 * SZ;               // Kproj

    unsigned short* scr = (unsigned short*)d_out;    // d_out as scratch (16M ushorts)
    unsigned short* WqT = scr;                       // [0,1M)
    unsigned short* WkT = scr + 1048576;             // [1M,2M)
    unsigned short* WvT = scr + 2097152;             // [2M,3M)
    unsigned short* Qb  = scr + 4194304;             // [4M,12M)

    const float qscale = 0.02209708691207961f * 1.44269504088896341f;

    // 1. q,k,v fp32 -> bf16
    const int n8 = (int)(SZ / 8);
    cvt3_kernel<<<dim3((n8 + 255) / 256, 3), 256, 0, stream>>>(q, k, v, ws0, ws1, ws2, n8);

    // 2. Wq/Wk/Wv transpose
    transpose_cvt3_kernel<<<dim3(16, 16, 3), 256, 0, stream>>>(Wq, WqT, Wk, WkT, Wv, WvT);

    // 3. Q and K projections (Q pre-scaled into exp2 domain)
    {
        GArg gq{ws0, WqT, bq, Qb,  qscale, 0};
        GArg gk{ws1, WkT, bk, ws3, 1.0f,   0};
        gemm_kernel<128><<<dim3(64, 8, 2), 256, 0, stream>>>(gq, gk, MROWS, DMODEL, DMODEL);
    }
    // 4. V projection directly into Vt layout -> ws0 (qb16 dead); 64x128 tile
    {
        GArg gv{ws2, WvT, bv, ws0, 1.0f, 3};
        gemm_kernel<64><<<dim3(128, 8, 1), 256, 0, stream>>>(gv, gv, MROWS, DMODEL, DMODEL);
    }
    // 5. Wf transpose -> ws2 (vb16 dead)
    transpose_cvt3_kernel<<<dim3(16, 16, 1), 256, 0, stream>>>(Wf, ws2, Wf, ws2, Wf, ws2);

    // 6. attention: Qb, Kproj(ws3), Vt(ws0) -> Cb(ws1)  (kb16 dead)
    attn_kernel<<<dim3(BB * NHEAD, 8), 512, 0, stream>>>(Qb, ws3, ws0, ws1);

    // 7. output projection: Cb @ WfT + bf -> d_out fp32; 64x128 tile
    {
        GArg gf{ws1, ws2, bf, (float*)d_out, 1.0f, 2};
        gemm_kernel<64><<<dim3(128, 8, 1), 256, 0, stream>>>(gf, gf, MROWS, DMODEL, DMODEL);
    }
}

// Round 15
// 193.292 us; speedup vs baseline: 1.2857x; 1.2857x over previous
//
#include <hip/hip_runtime.h>
#include <stdint.h>

#define DMODEL 1024
#define NHEAD 16
#define DH 64
#define BB 4
#define SS 2048
#define MROWS (BB * SS)   // 8192

typedef __bf16 bfx8 __attribute__((ext_vector_type(8)));
typedef float f32x4 __attribute__((ext_vector_type(4)));
typedef float fvec4 __attribute__((ext_vector_type(4)));
typedef int i32x4 __attribute__((ext_vector_type(4)));
typedef unsigned short u16x8 __attribute__((ext_vector_type(8)));
typedef unsigned short u16x4 __attribute__((ext_vector_type(4)));

__device__ __forceinline__ unsigned short f2bf(float f) {
    union { float f; unsigned int u; } v; v.f = f;
    unsigned int r = v.u + 0x7FFFu + ((v.u >> 16) & 1u);
    return (unsigned short)(r >> 16);
}

// packed fp32x2 -> bf16x2 (RNE), single HW instruction
__device__ __forceinline__ unsigned int cvtpk(float lo, float hi) {
    unsigned int r;
    asm("v_cvt_pk_bf16_f32 %0, %1, %2" : "=v"(r) : "v"(lo), "v"(hi));
    return r;
}

// async global->LDS, 16B per lane. LDS dest must be linear: wave base + lane*16.
typedef __attribute__((address_space(1))) const void gas_t;
typedef __attribute__((address_space(3))) void las_t;
__device__ __forceinline__ void gload_lds16(const void* g, void* l) {
    __builtin_amdgcn_global_load_lds((gas_t*)g, (las_t*)l, 16, 0, 0);
}

// K-row permutation for swapped-QK in-register P trick.
// i bits [nf1 nf0 lg1 lg0 r1 r0] -> sigma bits [nf1 lg1 lg0 nf0 r1 r0]
__device__ __forceinline__ int sigma_k(int i) {
    return (i & 0x20) | ((i & 0x0C) << 1) | ((i & 0x10) >> 2) | (i & 3);
}

// ---------------------------------------------------------------------------
// fp32 -> bf16 convert for q,k,v in one launch (blockIdx.y selects tensor)
// ---------------------------------------------------------------------------
__global__ void cvt3_kernel(const float* __restrict__ s0, const float* __restrict__ s1,
                            const float* __restrict__ s2,
                            unsigned short* __restrict__ d0, unsigned short* __restrict__ d1,
                            unsigned short* __restrict__ d2, int n8)
{
    const float* s = (blockIdx.y == 0) ? s0 : (blockIdx.y == 1) ? s1 : s2;
    unsigned short* d = (blockIdx.y == 0) ? d0 : (blockIdx.y == 1) ? d1 : d2;
    int i = blockIdx.x * blockDim.x + threadIdx.x;
    if (i >= n8) return;
    fvec4 a = *reinterpret_cast<const fvec4*>(&s[(size_t)i * 8]);
    fvec4 b = *reinterpret_cast<const fvec4*>(&s[(size_t)i * 8 + 4]);
    u16x8 o;
    #pragma unroll
    for (int j = 0; j < 4; ++j) { o[j] = f2bf(a[j]); o[j + 4] = f2bf(b[j]); }
    *reinterpret_cast<u16x8*>(&d[(size_t)i * 8]) = o;
}

// ---------------------------------------------------------------------------
// Transpose + convert: Wt[n][k] (bf16) = W[k][n] (fp32). 64x64 tiles.
// blockIdx.z selects which weight.
// ---------------------------------------------------------------------------
__global__ void transpose_cvt3_kernel(const float* __restrict__ W0, unsigned short* __restrict__ T0,
                                      const float* __restrict__ W1, unsigned short* __restrict__ T1,
                                      const float* __restrict__ W2, unsigned short* __restrict__ T2)
{
    const float* W = (blockIdx.z == 0) ? W0 : (blockIdx.z == 1) ? W1 : W2;
    unsigned short* Wt = (blockIdx.z == 0) ? T0 : (blockIdx.z == 1) ? T1 : T2;
    __shared__ unsigned short t[64][72];
    const int tid = threadIdx.x;
    const int r0 = blockIdx.y * 64, c0 = blockIdx.x * 64;
    #pragma unroll
    for (int i = 0; i < 4; ++i) {
        int idx = tid + i * 256;
        int r = idx >> 4, c4 = idx & 15;
        fvec4 v = *reinterpret_cast<const fvec4*>(&W[(size_t)(r0 + r) * DMODEL + c0 + c4 * 4]);
        #pragma unroll
        for (int j = 0; j < 4; ++j) t[c4 * 4 + j][r] = f2bf(v[j]);
    }
    __syncthreads();
    #pragma unroll
    for (int i = 0; i < 2; ++i) {
        int idx = tid + i * 256;
        int r = idx >> 3, c8 = idx & 7;
        u16x8 v = *reinterpret_cast<const u16x8*>(&t[r][c8 * 8]);
        *reinterpret_cast<u16x8*>(&Wt[(size_t)(c0 + r) * DMODEL + r0 + c8 * 8]) = v;
    }
}

// ---------------------------------------------------------------------------
// GEMM: out = A @ Bt^T + bias; bf16 in via global_load_lds.
// 128x128 tile, BK=64, 4 waves, per-kk fragment loads, launch_bounds(256,4).
// mode: 0 = bf16 row-major out, 2 = fp32 row-major out,
//       3 = bf16 Vt-layout out: O[((b*16+h)*64+d)*2048 + s] (per-head V^T)
// ---------------------------------------------------------------------------
struct GArg {
    const unsigned short* A;
    const unsigned short* Bt;
    const float* bias;
    void* O;
    float osc;
    int mode;
};

__global__ __launch_bounds__(256, 4)
void gemm_kernel(GArg g0, GArg g1, int M, int N, int K)
{
    const GArg g = blockIdx.z ? g1 : g0;
    __shared__ unsigned short sA[128 * 64];
    __shared__ unsigned short sB[128 * 64];
    const int tid  = threadIdx.x;
    const int lane = tid & 63;
    const int wave = tid >> 6;
    const int wm = (wave >> 1) * 64, wn = (wave & 1) * 64;
    const int m0 = blockIdx.x * 128, n0 = blockIdx.y * 128;
    const int lr = lane & 15;
    const int lg = lane >> 4;

    f32x4 acc[4][4] = {};

    for (int kk0 = 0; kk0 < K; kk0 += 64) {
        __syncthreads();
        #pragma unroll
        for (int i = 0; i < 4; ++i) {
            int c = tid + i * 256;
            int row = c >> 3, col8 = c & 7;
            gload_lds16(&g.A[(size_t)(m0 + row) * K + kk0 + col8 * 8], &sA[c * 8]);
        }
        #pragma unroll
        for (int i = 0; i < 4; ++i) {
            int c = tid + i * 256;
            int row = c >> 3, col8 = c & 7;
            gload_lds16(&g.Bt[(size_t)(n0 + row) * K + kk0 + col8 * 8], &sB[c * 8]);
        }
        __syncthreads();

        #pragma unroll
        for (int kk = 0; kk < 2; ++kk) {
            bfx8 af[4], bfr[4];
            #pragma unroll
            for (int m = 0; m < 4; ++m)
                af[m] = *reinterpret_cast<const bfx8*>(
                    &sA[(wm + m * 16 + lr) * 64 + kk * 32 + lg * 8]);
            #pragma unroll
            for (int n = 0; n < 4; ++n)
                bfr[n] = *reinterpret_cast<const bfx8*>(
                    &sB[(wn + n * 16 + lr) * 64 + kk * 32 + lg * 8]);
            #pragma unroll
            for (int m = 0; m < 4; ++m)
                #pragma unroll
                for (int n = 0; n < 4; ++n)
                    acc[m][n] = __builtin_amdgcn_mfma_f32_16x16x32_bf16(
                        af[m], bfr[n], acc[m][n], 0, 0, 0);
        }
    }

    #pragma unroll
    for (int n = 0; n < 4; ++n) {
        int col = n0 + wn + n * 16 + lr;
        float bv = g.bias[col];
        #pragma unroll
        for (int m = 0; m < 4; ++m) {
            int rowb = m0 + wm + m * 16 + lg * 4;
            float val[4];
            #pragma unroll
            for (int r = 0; r < 4; ++r) val[r] = (acc[m][n][r] + bv) * g.osc;
            if (g.mode == 0) {
                #pragma unroll
                for (int r = 0; r < 4; ++r)
                    ((unsigned short*)g.O)[(size_t)(rowb + r) * N + col] = f2bf(val[r]);
            } else if (g.mode == 2) {
                #pragma unroll
                for (int r = 0; r < 4; ++r)
                    ((float*)g.O)[(size_t)(rowb + r) * N + col] = val[r];
            } else {
                // Vt layout: rows rowb..rowb+3 are consecutive s in one batch
                int bq = rowb >> 11, s = rowb & 2047;
                int hh = col >> 6, d = col & 63;
                u16x4 pk;
                #pragma unroll
                for (int r = 0; r < 4; ++r) pk[r] = f2bf(val[r]);
                size_t idx = ((size_t)(bq * 16 + hh) * 64 + d) * 2048 + s;
                *reinterpret_cast<u16x4*>(&((unsigned short*)g.O)[idx]) = pk;
            }
        }
    }
}

// ---------------------------------------------------------------------------
// Flash-style causal attention (R13 body + single-barrier double-buffered
// staging). 8-wave (512-thr) blocks, QBLK=128, wave owns 16 q-rows;
// balanced q-tile pair {15-p, p} processed sequentially (ph loop).
// Pair-buffers double-buffered: one barrier per 2-k-tile pair; loads for
// pair u+2 issued at u (full-iteration latency hiding).
// l via ones-MFMA (C-layout, shuffle-free epilogue); max3 pmax tree;
// swizzled conflict-free LDS; sigma-permuted K rows; in-register P.
// Q pre-scaled by 1/sqrt(2048)*log2(e). Q,K: [B*S][H*DH]; Vt: [B*H][DH][S].
// ---------------------------------------------------------------------------
__global__ __launch_bounds__(512, 4)
void attn_kernel(const unsigned short* __restrict__ Q,
                 const unsigned short* __restrict__ K,
                 const unsigned short* __restrict__ Vt,
                 unsigned short* __restrict__ C)
{
    __shared__ unsigned short sK[2][8192];   // [pairbuf][tile s*4096 + off]
    __shared__ unsigned short sV[2][8192];

    const int tid  = threadIdx.x;                // 0..511
    const int lane = tid & 63;
    const int wave = tid >> 6;                   // 0..7
    const int lr = lane & 15, lg = lane >> 4;
    const int bh = blockIdx.x;
    const int p  = blockIdx.y;                   // pair index 0..7
    const int b = bh >> 4, h = bh & 15;
    const size_t rowbase = (size_t)b * SS;
    const int hcol = h * DH;

    // staging coords: one 8-elem chunk per thread (64 rows x 8 chunks = 512)
    const int srow = tid >> 3, sc8 = tid & 7;
    const int sig  = sigma_k(srow);
    const int woff = srow * 64 + ((sc8 ^ (srow & 7)) * 8);
    const int p0 = lg ^ (lr & 7);                // swizzled chunk for QK reads

    const u16x8 onesu = {0x3F80, 0x3F80, 0x3F80, 0x3F80, 0x3F80, 0x3F80, 0x3F80, 0x3F80};
    union { u16x8 u; bfx8 b; } onesc; onesc.u = onesu;
    const bfx8 ones = onesc.b;

    #pragma unroll
    for (int ph = 0; ph < 2; ++ph) {
        const int qt = ph ? p : (15 - p);
        const int q0 = qt * 128;

        // Q fragment: wave's 16 q-rows, 2 d-chunks (B-operand of swapped mfma)
        bfx8 aq[2];
        {
            int qr = q0 + wave * 16 + lr;
            const unsigned short* qp = &Q[(rowbase + qr) * DMODEL + hcol + lg * 8];
            aq[0] = *reinterpret_cast<const bfx8*>(qp);
            aq[1] = *reinterpret_cast<const bfx8*>(qp + 32);
        }

        float m_run = 0.f;                       // per-lane (q = lr), exp2 domain
        f32x4 acc_l = {};                        // l in C-layout (row = lg*4+r)
        f32x4 acc_o[4] = {};
        bool mz = true;
        const int qmax_wave = q0 + wave * 16 + 15;
        const int npairs = qt + 1;               // k-tiles = 2*npairs

        u16x8 rk[2], rv[2];
        // ---- prologue: pair 0 -> regs -> buf0; then issue pair-1 loads
        #pragma unroll
        for (int s = 0; s < 2; ++s) {
            rk[s] = *reinterpret_cast<const u16x8*>(
                &K[(rowbase + s * 64 + sig) * DMODEL + hcol + sc8 * 8]);
            rv[s] = *reinterpret_cast<const u16x8*>(
                &Vt[((size_t)bh * DH + srow) * SS + s * 64 + sc8 * 8]);
        }
        #pragma unroll
        for (int s = 0; s < 2; ++s) {
            *reinterpret_cast<u16x8*>(&sK[0][s * 4096 + woff]) = rk[s];
            *reinterpret_cast<u16x8*>(&sV[0][s * 4096 + woff]) = rv[s];
        }
        if (npairs > 1) {
            #pragma unroll
            for (int s = 0; s < 2; ++s) {
                const int kk = (2 + s) * 64;
                rk[s] = *reinterpret_cast<const u16x8*>(
                    &K[(rowbase + kk + sig) * DMODEL + hcol + sc8 * 8]);
                rv[s] = *reinterpret_cast<const u16x8*>(
                    &Vt[((size_t)bh * DH + srow) * SS + kk + sc8 * 8]);
            }
        }
        __syncthreads();

        for (int u = 0; u < npairs; ++u) {
            const int cur = u & 1;
            // ---- compute both tiles of pair u from buf[cur]
            #pragma unroll
            for (int s = 0; s < 2; ++s) {
                const int k0 = (2 * u + s) * 64;
                if (k0 > qmax_wave) break;

                f32x4 sc[4];
                __builtin_amdgcn_s_setprio(1);
                #pragma unroll
                for (int nf = 0; nf < 4; ++nf) {
                    int i = nf * 16 + lr;
                    bfx8 ak0 = *reinterpret_cast<const bfx8*>(&sK[cur][s * 4096 + i * 64 + p0 * 8]);
                    bfx8 ak1 = *reinterpret_cast<const bfx8*>(&sK[cur][s * 4096 + i * 64 + (p0 ^ 4) * 8]);
                    f32x4 sv = {0.f, 0.f, 0.f, 0.f};
                    sv = __builtin_amdgcn_mfma_f32_16x16x32_bf16(ak0, aq[0], sv, 0, 0, 0);
                    sv = __builtin_amdgcn_mfma_f32_16x16x32_bf16(ak1, aq[1], sv, 0, 0, 0);
                    sc[nf] = sv;
                }
                __builtin_amdgcn_s_setprio(0);
                // causal mask (diagonal-overlapping tiles only)
                if (k0 + 63 > q0 + wave * 16) {
                    int qrow = q0 + wave * 16 + lr;
                    #pragma unroll
                    for (int nf = 0; nf < 4; ++nf) {
                        int kb = k0 + ((nf >> 1) << 5) + (lg << 3) + ((nf & 1) << 2);
                        #pragma unroll
                        for (int r = 0; r < 4; ++r)
                            if (kb + r > qrow) sc[nf][r] = -3.0e38f;
                    }
                }
                // pmax via max3-friendly triples
                float a0 = fmaxf(fmaxf(sc[0][0], sc[0][1]), sc[0][2]);
                float a1 = fmaxf(fmaxf(sc[0][3], sc[1][0]), sc[1][1]);
                float a2 = fmaxf(fmaxf(sc[1][2], sc[1][3]), sc[2][0]);
                float a3 = fmaxf(fmaxf(sc[2][1], sc[2][2]), sc[2][3]);
                float a4 = fmaxf(fmaxf(sc[3][0], sc[3][1]), sc[3][2]);
                float pmax = fmaxf(fmaxf(fmaxf(a0, a1), fmaxf(a2, a3)),
                                   fmaxf(a4, sc[3][3]));
                if (mz && __all(pmax <= 8.0f)) {
                    #pragma unroll
                    for (int nf = 0; nf < 4; ++nf)
                        #pragma unroll
                        for (int r = 0; r < 4; ++r)
                            sc[nf][r] = __builtin_exp2f(sc[nf][r]);
                } else {
                    mz = false;
                    float mx = pmax;
                    mx = fmaxf(mx, __shfl_xor(mx, 16, 64));
                    mx = fmaxf(mx, __shfl_xor(mx, 32, 64));
                    float mnew = fmaxf(m_run, mx);
                    float fs = __builtin_exp2f(m_run - mnew);
                    m_run = mnew;
                    #pragma unroll
                    for (int nf = 0; nf < 4; ++nf)
                        #pragma unroll
                        for (int r = 0; r < 4; ++r)
                            sc[nf][r] = __builtin_exp2f(sc[nf][r] - mnew);
                    #pragma unroll
                    for (int r = 0; r < 4; ++r) {
                        float fsa = __shfl(fs, lg * 4 + r, 64);
                        #pragma unroll
                        for (int d = 0; d < 4; ++d) acc_o[d][r] *= fsa;
                        acc_l[r] *= fsa;
                    }
                }
                // pack P in-register; PV + l via MFMA
                #pragma unroll
                for (int h2 = 0; h2 < 2; ++h2) {
                    union { i32x4 i; bfx8 b; } pa;
                    pa.i[0] = cvtpk(sc[2 * h2][0],     sc[2 * h2][1]);
                    pa.i[1] = cvtpk(sc[2 * h2][2],     sc[2 * h2][3]);
                    pa.i[2] = cvtpk(sc[2 * h2 + 1][0], sc[2 * h2 + 1][1]);
                    pa.i[3] = cvtpk(sc[2 * h2 + 1][2], sc[2 * h2 + 1][3]);
                    __builtin_amdgcn_s_setprio(1);
                    acc_l = __builtin_amdgcn_mfma_f32_16x16x32_bf16(pa.b, ones, acc_l, 0, 0, 0);
                    #pragma unroll
                    for (int d = 0; d < 4; ++d) {
                        int i = d * 16 + lr;
                        int pv = ((h2 << 2) | lg) ^ (lr & 7);
                        bfx8 bv0 = *reinterpret_cast<const bfx8*>(&sV[cur][s * 4096 + i * 64 + pv * 8]);
                        acc_o[d] = __builtin_amdgcn_mfma_f32_16x16x32_bf16(pa.b, bv0, acc_o[d], 0, 0, 0);
                    }
                    __builtin_amdgcn_s_setprio(0);
                }
            }
            // ---- write pair u+1 into the other buffer (its last reader was
            // iteration u-1, protected by that iteration's barrier), then
            // issue loads for pair u+2; single barrier per pair.
            if (u + 1 < npairs) {
                #pragma unroll
                for (int s = 0; s < 2; ++s) {
                    *reinterpret_cast<u16x8*>(&sK[cur ^ 1][s * 4096 + woff]) = rk[s];
                    *reinterpret_cast<u16x8*>(&sV[cur ^ 1][s * 4096 + woff]) = rv[s];
                }
                if (u + 2 < npairs) {
                    #pragma unroll
                    for (int s = 0; s < 2; ++s) {
                        const int kk = (2 * u + 4 + s) * 64;
                        rk[s] = *reinterpret_cast<const u16x8*>(
                            &K[(rowbase + kk + sig) * DMODEL + hcol + sc8 * 8]);
                        rv[s] = *reinterpret_cast<const u16x8*>(
                            &Vt[((size_t)bh * DH + srow) * SS + kk + sc8 * 8]);
                    }
                }
            }
            __syncthreads();
        }

        // ---- epilogue: shuffle-free (acc_l shares acc_o's C-layout rows)
        f32x4 linv;
        #pragma unroll
        for (int r = 0; r < 4; ++r) linv[r] = 1.0f / acc_l[r];
        const int qrb = q0 + wave * 16 + lg * 4;
        #pragma unroll
        for (int d = 0; d < 4; ++d) {
            int col = hcol + d * 16 + lr;
            #pragma unroll
            for (int r = 0; r < 4; ++r)
                C[(rowbase + qrb + r) * DMODEL + col] = f2bf(acc_o[d][r] * linv[r]);
        }
    }
}

// ---------------------------------------------------------------------------
extern "C" void kernel_launch(void* const* d_in, const int* in_sizes, int n_in,
                              void* d_out, int out_size, void* d_ws, size_t ws_size,
                              hipStream_t stream)
{
    const float* q  = (const float*)d_in[0];
    const float* k  = (const float*)d_in[1];
    const float* v  = (const float*)d_in[2];
    const float* Wq = (const float*)d_in[3];
    const float* bq = (const float*)d_in[4];
    const float* Wk = (const float*)d_in[5];
    const float* bk = (const float*)d_in[6];
    const float* Wv = (const float*)d_in[7];
    const float* bv = (const float*)d_in[8];
    const float* Wf = (const float*)d_in[9];
    const float* bf = (const float*)d_in[10];

    unsigned short* ws = (unsigned short*)d_ws;
    const size_t SZ = (size_t)MROWS * DMODEL;        // 8388608 elems
    unsigned short* ws0 = ws;                        // qb16 -> Vt -> (dead)
    unsigned short* ws1 = ws + SZ;                   // kb16 -> Cb
    unsigned short* ws2 = ws + 2 * SZ;               // vb16 -> WfT
    unsigned short* ws3 = ws + 3 * SZ;               // Kproj

    unsigned short* scr = (unsigned short*)d_out;    // d_out as scratch (16M ushorts)
    unsigned short* WqT = scr;                       // [0,1M)
    unsigned short* WkT = scr + 1048576;             // [1M,2M)
    unsigned short* WvT = scr + 2097152;             // [2M,3M)
    unsigned short* Qb  = scr + 4194304;             // [4M,12M)

    const float qscale = 0.02209708691207961f * 1.44269504088896341f;

    // 1. q,k,v fp32 -> bf16
    const int n8 = (int)(SZ / 8);
    cvt3_kernel<<<dim3((n8 + 255) / 256, 3), 256, 0, stream>>>(q, k, v, ws0, ws1, ws2, n8);

    // 2. Wq/Wk/Wv transpose
    transpose_cvt3_kernel<<<dim3(16, 16, 3), 256, 0, stream>>>(Wq, WqT, Wk, WkT, Wv, WvT);

    // 3. Q and K projections (Q pre-scaled into exp2 domain)
    {
        GArg gq{ws0, WqT, bq, Qb,  qscale, 0};
        GArg gk{ws1, WkT, bk, ws3, 1.0f,   0};
        gemm_kernel<<<dim3(64, 8, 2), 256, 0, stream>>>(gq, gk, MROWS, DMODEL, DMODEL);
    }
    // 4. V projection directly into Vt layout -> ws0 (qb16 dead)
    {
        GArg gv{ws2, WvT, bv, ws0, 1.0f, 3};
        gemm_kernel<<<dim3(64, 8, 1), 256, 0, stream>>>(gv, gv, MROWS, DMODEL, DMODEL);
    }
    // 5. Wf transpose -> ws2 (vb16 dead)
    transpose_cvt3_kernel<<<dim3(16, 16, 1), 256, 0, stream>>>(Wf, ws2, Wf, ws2, Wf, ws2);

    // 6. attention: Qb, Kproj(ws3), Vt(ws0) -> Cb(ws1)  (kb16 dead)
    attn_kernel<<<dim3(BB * NHEAD, 8), 512, 0, stream>>>(Qb, ws3, ws0, ws1);

    // 7. output projection: Cb @ WfT + bf -> d_out fp32 (scratch regions dead)
    {
        GArg gf{ws1, ws2, bf, (float*)d_out, 1.0f, 2};
        gemm_kernel<<<dim3(64, 8, 1), 256, 0, stream>>>(gf, gf, MROWS, DMODEL, DMODEL);
    }
}

// Round 16
// 185.193 us; speedup vs baseline: 1.3420x; 1.0437x over previous
//
#include <hip/hip_runtime.h>
#include <stdint.h>

#define DMODEL 1024
#define NHEAD 16
#define DH 64
#define BB 4
#define SS 2048
#define MROWS (BB * SS)   // 8192

typedef __bf16 bfx8 __attribute__((ext_vector_type(8)));
typedef float f32x4 __attribute__((ext_vector_type(4)));
typedef float fvec4 __attribute__((ext_vector_type(4)));
typedef int i32x4 __attribute__((ext_vector_type(4)));
typedef unsigned short u16x8 __attribute__((ext_vector_type(8)));
typedef unsigned short u16x4 __attribute__((ext_vector_type(4)));

__device__ __forceinline__ unsigned short f2bf(float f) {
    union { float f; unsigned int u; } v; v.f = f;
    unsigned int r = v.u + 0x7FFFu + ((v.u >> 16) & 1u);
    return (unsigned short)(r >> 16);
}

// packed fp32x2 -> bf16x2 (RNE), single HW instruction
__device__ __forceinline__ unsigned int cvtpk(float lo, float hi) {
    unsigned int r;
    asm("v_cvt_pk_bf16_f32 %0, %1, %2" : "=v"(r) : "v"(lo), "v"(hi));
    return r;
}

// async global->LDS, 16B per lane. LDS dest must be linear: wave base + lane*16.
typedef __attribute__((address_space(1))) const void gas_t;
typedef __attribute__((address_space(3))) void las_t;
__device__ __forceinline__ void gload_lds16(const void* g, void* l) {
    __builtin_amdgcn_global_load_lds((gas_t*)g, (las_t*)l, 16, 0, 0);
}

// K-row permutation for swapped-QK in-register P trick.
// i bits [nf1 nf0 lg1 lg0 r1 r0] -> sigma bits [nf1 lg1 lg0 nf0 r1 r0]
__device__ __forceinline__ int sigma_k(int i) {
    return (i & 0x20) | ((i & 0x0C) << 1) | ((i & 0x10) >> 2) | (i & 3);
}

// ---------------------------------------------------------------------------
// Transpose + convert: Wt[n][k] (bf16) = W[k][n] (fp32). 64x64 tiles.
// blockIdx.z selects which of FOUR weights (one launch for all).
// ---------------------------------------------------------------------------
__global__ void transpose_cvt4_kernel(const float* __restrict__ W0, unsigned short* __restrict__ T0,
                                      const float* __restrict__ W1, unsigned short* __restrict__ T1,
                                      const float* __restrict__ W2, unsigned short* __restrict__ T2,
                                      const float* __restrict__ W3, unsigned short* __restrict__ T3)
{
    const float* W = (blockIdx.z == 0) ? W0 : (blockIdx.z == 1) ? W1
                   : (blockIdx.z == 2) ? W2 : W3;
    unsigned short* Wt = (blockIdx.z == 0) ? T0 : (blockIdx.z == 1) ? T1
                       : (blockIdx.z == 2) ? T2 : T3;
    __shared__ unsigned short t[64][72];
    const int tid = threadIdx.x;
    const int r0 = blockIdx.y * 64, c0 = blockIdx.x * 64;
    #pragma unroll
    for (int i = 0; i < 4; ++i) {
        int idx = tid + i * 256;
        int r = idx >> 4, c4 = idx & 15;
        fvec4 v = *reinterpret_cast<const fvec4*>(&W[(size_t)(r0 + r) * DMODEL + c0 + c4 * 4]);
        #pragma unroll
        for (int j = 0; j < 4; ++j) t[c4 * 4 + j][r] = f2bf(v[j]);
    }
    __syncthreads();
    #pragma unroll
    for (int i = 0; i < 2; ++i) {
        int idx = tid + i * 256;
        int r = idx >> 3, c8 = idx & 7;
        u16x8 v = *reinterpret_cast<const u16x8*>(&t[r][c8 * 8]);
        *reinterpret_cast<u16x8*>(&Wt[(size_t)(c0 + r) * DMODEL + r0 + c8 * 8]) = v;
    }
}

// ---------------------------------------------------------------------------
// GEMM: out = A @ Bt^T + bias; Bt bf16 via global_load_lds.
// A_FP32: A is fp32, reg-staged with v_cvt_pk_bf16_f32 (fuses the convert
// pass into the projection); else A bf16 via global_load_lds.
// 128x128 tile, BK=64, 4 waves, per-kk fragment loads, launch_bounds(256,4).
// mode: 0 = bf16 row-major out, 2 = fp32 row-major out,
//       3 = bf16 Vt-layout out: O[((b*16+h)*64+d)*2048 + s] (per-head V^T)
// ---------------------------------------------------------------------------
struct GArg {
    const void* A;
    const unsigned short* Bt;
    const float* bias;
    void* O;
    float osc;
    int mode;
};

template<bool A_FP32>
__global__ __launch_bounds__(256, 4)
void gemm_kernel(GArg g0, GArg g1, GArg g2, int M, int N, int K)
{
    const GArg g = (blockIdx.z == 0) ? g0 : (blockIdx.z == 1) ? g1 : g2;
    __shared__ unsigned short sA[128 * 64];
    __shared__ unsigned short sB[128 * 64];
    const int tid  = threadIdx.x;
    const int lane = tid & 63;
    const int wave = tid >> 6;
    const int wm = (wave >> 1) * 64, wn = (wave & 1) * 64;
    const int m0 = blockIdx.x * 128, n0 = blockIdx.y * 128;
    const int lr = lane & 15;
    const int lg = lane >> 4;

    f32x4 acc[4][4] = {};

    for (int kk0 = 0; kk0 < K; kk0 += 64) {
        __syncthreads();
        if (A_FP32) {
            const float* Af = (const float*)g.A;
            #pragma unroll
            for (int i = 0; i < 4; ++i) {
                int c = tid + i * 256;
                int row = c >> 3, col8 = c & 7;
                const float* src = &Af[(size_t)(m0 + row) * K + kk0 + col8 * 8];
                fvec4 x = *reinterpret_cast<const fvec4*>(src);
                fvec4 y = *reinterpret_cast<const fvec4*>(src + 4);
                union { i32x4 i; u16x8 u; } pk;
                pk.i[0] = cvtpk(x[0], x[1]);
                pk.i[1] = cvtpk(x[2], x[3]);
                pk.i[2] = cvtpk(y[0], y[1]);
                pk.i[3] = cvtpk(y[2], y[3]);
                *reinterpret_cast<u16x8*>(&sA[c * 8]) = pk.u;
            }
        } else {
            const unsigned short* Ab = (const unsigned short*)g.A;
            #pragma unroll
            for (int i = 0; i < 4; ++i) {
                int c = tid + i * 256;
                int row = c >> 3, col8 = c & 7;
                gload_lds16(&Ab[(size_t)(m0 + row) * K + kk0 + col8 * 8], &sA[c * 8]);
            }
        }
        #pragma unroll
        for (int i = 0; i < 4; ++i) {
            int c = tid + i * 256;
            int row = c >> 3, col8 = c & 7;
            gload_lds16(&g.Bt[(size_t)(n0 + row) * K + kk0 + col8 * 8], &sB[c * 8]);
        }
        __syncthreads();

        #pragma unroll
        for (int kk = 0; kk < 2; ++kk) {
            bfx8 af[4], bfr[4];
            #pragma unroll
            for (int m = 0; m < 4; ++m)
                af[m] = *reinterpret_cast<const bfx8*>(
                    &sA[(wm + m * 16 + lr) * 64 + kk * 32 + lg * 8]);
            #pragma unroll
            for (int n = 0; n < 4; ++n)
                bfr[n] = *reinterpret_cast<const bfx8*>(
                    &sB[(wn + n * 16 + lr) * 64 + kk * 32 + lg * 8]);
            #pragma unroll
            for (int m = 0; m < 4; ++m)
                #pragma unroll
                for (int n = 0; n < 4; ++n)
                    acc[m][n] = __builtin_amdgcn_mfma_f32_16x16x32_bf16(
                        af[m], bfr[n], acc[m][n], 0, 0, 0);
        }
    }

    #pragma unroll
    for (int n = 0; n < 4; ++n) {
        int col = n0 + wn + n * 16 + lr;
        float bv = g.bias[col];
        #pragma unroll
        for (int m = 0; m < 4; ++m) {
            int rowb = m0 + wm + m * 16 + lg * 4;
            float val[4];
            #pragma unroll
            for (int r = 0; r < 4; ++r) val[r] = (acc[m][n][r] + bv) * g.osc;
            if (g.mode == 0) {
                #pragma unroll
                for (int r = 0; r < 4; ++r)
                    ((unsigned short*)g.O)[(size_t)(rowb + r) * N + col] = f2bf(val[r]);
            } else if (g.mode == 2) {
                #pragma unroll
                for (int r = 0; r < 4; ++r)
                    ((float*)g.O)[(size_t)(rowb + r) * N + col] = val[r];
            } else {
                // Vt layout: rows rowb..rowb+3 are consecutive s in one batch
                int bq = rowb >> 11, s = rowb & 2047;
                int hh = col >> 6, d = col & 63;
                u16x4 pk;
                #pragma unroll
                for (int r = 0; r < 4; ++r) pk[r] = f2bf(val[r]);
                size_t idx = ((size_t)(bq * 16 + hh) * 64 + d) * 2048 + s;
                *reinterpret_cast<u16x4*>(&((unsigned short*)g.O)[idx]) = pk;
            }
        }
    }
}

// ---------------------------------------------------------------------------
// Flash-style causal attention (R15: single-barrier double-buffered pairs).
// 8-wave (512-thr) blocks, QBLK=128, wave owns 16 q-rows; balanced q-tile
// pair {15-p, p} processed sequentially. l via ones-MFMA; max3 pmax tree;
// swizzled conflict-free LDS; sigma-permuted K rows; in-register P.
// Q pre-scaled by 1/sqrt(2048)*log2(e). Q,K: [B*S][H*DH]; Vt: [B*H][DH][S].
// ---------------------------------------------------------------------------
__global__ __launch_bounds__(512, 4)
void attn_kernel(const unsigned short* __restrict__ Q,
                 const unsigned short* __restrict__ K,
                 const unsigned short* __restrict__ Vt,
                 unsigned short* __restrict__ C)
{
    __shared__ unsigned short sK[2][8192];   // [pairbuf][tile s*4096 + off]
    __shared__ unsigned short sV[2][8192];

    const int tid  = threadIdx.x;                // 0..511
    const int lane = tid & 63;
    const int wave = tid >> 6;                   // 0..7
    const int lr = lane & 15, lg = lane >> 4;
    const int bh = blockIdx.x;
    const int p  = blockIdx.y;                   // pair index 0..7
    const int b = bh >> 4, h = bh & 15;
    const size_t rowbase = (size_t)b * SS;
    const int hcol = h * DH;

    // staging coords: one 8-elem chunk per thread (64 rows x 8 chunks = 512)
    const int srow = tid >> 3, sc8 = tid & 7;
    const int sig  = sigma_k(srow);
    const int woff = srow * 64 + ((sc8 ^ (srow & 7)) * 8);
    const int p0 = lg ^ (lr & 7);                // swizzled chunk for QK reads

    const u16x8 onesu = {0x3F80, 0x3F80, 0x3F80, 0x3F80, 0x3F80, 0x3F80, 0x3F80, 0x3F80};
    union { u16x8 u; bfx8 b; } onesc; onesc.u = onesu;
    const bfx8 ones = onesc.b;

    #pragma unroll
    for (int ph = 0; ph < 2; ++ph) {
        const int qt = ph ? p : (15 - p);
        const int q0 = qt * 128;

        // Q fragment: wave's 16 q-rows, 2 d-chunks (B-operand of swapped mfma)
        bfx8 aq[2];
        {
            int qr = q0 + wave * 16 + lr;
            const unsigned short* qp = &Q[(rowbase + qr) * DMODEL + hcol + lg * 8];
            aq[0] = *reinterpret_cast<const bfx8*>(qp);
            aq[1] = *reinterpret_cast<const bfx8*>(qp + 32);
        }

        float m_run = 0.f;                       // per-lane (q = lr), exp2 domain
        f32x4 acc_l = {};                        // l in C-layout (row = lg*4+r)
        f32x4 acc_o[4] = {};
        bool mz = true;
        const int qmax_wave = q0 + wave * 16 + 15;
        const int npairs = qt + 1;               // k-tiles = 2*npairs

        u16x8 rk[2], rv[2];
        // ---- prologue: pair 0 -> regs -> buf0; then issue pair-1 loads
        #pragma unroll
        for (int s = 0; s < 2; ++s) {
            rk[s] = *reinterpret_cast<const u16x8*>(
                &K[(rowbase + s * 64 + sig) * DMODEL + hcol + sc8 * 8]);
            rv[s] = *reinterpret_cast<const u16x8*>(
                &Vt[((size_t)bh * DH + srow) * SS + s * 64 + sc8 * 8]);
        }
        #pragma unroll
        for (int s = 0; s < 2; ++s) {
            *reinterpret_cast<u16x8*>(&sK[0][s * 4096 + woff]) = rk[s];
            *reinterpret_cast<u16x8*>(&sV[0][s * 4096 + woff]) = rv[s];
        }
        if (npairs > 1) {
            #pragma unroll
            for (int s = 0; s < 2; ++s) {
                const int kk = (2 + s) * 64;
                rk[s] = *reinterpret_cast<const u16x8*>(
                    &K[(rowbase + kk + sig) * DMODEL + hcol + sc8 * 8]);
                rv[s] = *reinterpret_cast<const u16x8*>(
                    &Vt[((size_t)bh * DH + srow) * SS + kk + sc8 * 8]);
            }
        }
        __syncthreads();

        for (int u = 0; u < npairs; ++u) {
            const int cur = u & 1;
            // ---- compute both tiles of pair u from buf[cur]
            #pragma unroll
            for (int s = 0; s < 2; ++s) {
                const int k0 = (2 * u + s) * 64;
                if (k0 > qmax_wave) break;

                f32x4 sc[4];
                __builtin_amdgcn_s_setprio(1);
                #pragma unroll
                for (int nf = 0; nf < 4; ++nf) {
                    int i = nf * 16 + lr;
                    bfx8 ak0 = *reinterpret_cast<const bfx8*>(&sK[cur][s * 4096 + i * 64 + p0 * 8]);
                    bfx8 ak1 = *reinterpret_cast<const bfx8*>(&sK[cur][s * 4096 + i * 64 + (p0 ^ 4) * 8]);
                    f32x4 sv = {0.f, 0.f, 0.f, 0.f};
                    sv = __builtin_amdgcn_mfma_f32_16x16x32_bf16(ak0, aq[0], sv, 0, 0, 0);
                    sv = __builtin_amdgcn_mfma_f32_16x16x32_bf16(ak1, aq[1], sv, 0, 0, 0);
                    sc[nf] = sv;
                }
                __builtin_amdgcn_s_setprio(0);
                // causal mask (diagonal-overlapping tiles only)
                if (k0 + 63 > q0 + wave * 16) {
                    int qrow = q0 + wave * 16 + lr;
                    #pragma unroll
                    for (int nf = 0; nf < 4; ++nf) {
                        int kb = k0 + ((nf >> 1) << 5) + (lg << 3) + ((nf & 1) << 2);
                        #pragma unroll
                        for (int r = 0; r < 4; ++r)
                            if (kb + r > qrow) sc[nf][r] = -3.0e38f;
                    }
                }
                // pmax via max3-friendly triples
                float a0 = fmaxf(fmaxf(sc[0][0], sc[0][1]), sc[0][2]);
                float a1 = fmaxf(fmaxf(sc[0][3], sc[1][0]), sc[1][1]);
                float a2 = fmaxf(fmaxf(sc[1][2], sc[1][3]), sc[2][0]);
                float a3 = fmaxf(fmaxf(sc[2][1], sc[2][2]), sc[2][3]);
                float a4 = fmaxf(fmaxf(sc[3][0], sc[3][1]), sc[3][2]);
                float pmax = fmaxf(fmaxf(fmaxf(a0, a1), fmaxf(a2, a3)),
                                   fmaxf(a4, sc[3][3]));
                if (mz && __all(pmax <= 8.0f)) {
                    #pragma unroll
                    for (int nf = 0; nf < 4; ++nf)
                        #pragma unroll
                        for (int r = 0; r < 4; ++r)
                            sc[nf][r] = __builtin_exp2f(sc[nf][r]);
                } else {
                    mz = false;
                    float mx = pmax;
                    mx = fmaxf(mx, __shfl_xor(mx, 16, 64));
                    mx = fmaxf(mx, __shfl_xor(mx, 32, 64));
                    float mnew = fmaxf(m_run, mx);
                    float fs = __builtin_exp2f(m_run - mnew);
                    m_run = mnew;
                    #pragma unroll
                    for (int nf = 0; nf < 4; ++nf)
                        #pragma unroll
                        for (int r = 0; r < 4; ++r)
                            sc[nf][r] = __builtin_exp2f(sc[nf][r] - mnew);
                    #pragma unroll
                    for (int r = 0; r < 4; ++r) {
                        float fsa = __shfl(fs, lg * 4 + r, 64);
                        #pragma unroll
                        for (int d = 0; d < 4; ++d) acc_o[d][r] *= fsa;
                        acc_l[r] *= fsa;
                    }
                }
                // pack P in-register; PV + l via MFMA
                #pragma unroll
                for (int h2 = 0; h2 < 2; ++h2) {
                    union { i32x4 i; bfx8 b; } pa;
                    pa.i[0] = cvtpk(sc[2 * h2][0],     sc[2 * h2][1]);
                    pa.i[1] = cvtpk(sc[2 * h2][2],     sc[2 * h2][3]);
                    pa.i[2] = cvtpk(sc[2 * h2 + 1][0], sc[2 * h2 + 1][1]);
                    pa.i[3] = cvtpk(sc[2 * h2 + 1][2], sc[2 * h2 + 1][3]);
                    __builtin_amdgcn_s_setprio(1);
                    acc_l = __builtin_amdgcn_mfma_f32_16x16x32_bf16(pa.b, ones, acc_l, 0, 0, 0);
                    #pragma unroll
                    for (int d = 0; d < 4; ++d) {
                        int i = d * 16 + lr;
                        int pv = ((h2 << 2) | lg) ^ (lr & 7);
                        bfx8 bv0 = *reinterpret_cast<const bfx8*>(&sV[cur][s * 4096 + i * 64 + pv * 8]);
                        acc_o[d] = __builtin_amdgcn_mfma_f32_16x16x32_bf16(pa.b, bv0, acc_o[d], 0, 0, 0);
                    }
                    __builtin_amdgcn_s_setprio(0);
                }
            }
            // ---- write pair u+1 into the other buffer, issue loads for u+2
            if (u + 1 < npairs) {
                #pragma unroll
                for (int s = 0; s < 2; ++s) {
                    *reinterpret_cast<u16x8*>(&sK[cur ^ 1][s * 4096 + woff]) = rk[s];
                    *reinterpret_cast<u16x8*>(&sV[cur ^ 1][s * 4096 + woff]) = rv[s];
                }
                if (u + 2 < npairs) {
                    #pragma unroll
                    for (int s = 0; s < 2; ++s) {
                        const int kk = (2 * u + 4 + s) * 64;
                        rk[s] = *reinterpret_cast<const u16x8*>(
                            &K[(rowbase + kk + sig) * DMODEL + hcol + sc8 * 8]);
                        rv[s] = *reinterpret_cast<const u16x8*>(
                            &Vt[((size_t)bh * DH + srow) * SS + kk + sc8 * 8]);
                    }
                }
            }
            __syncthreads();
        }

        // ---- epilogue: shuffle-free (acc_l shares acc_o's C-layout rows)
        f32x4 linv;
        #pragma unroll
        for (int r = 0; r < 4; ++r) linv[r] = 1.0f / acc_l[r];
        const int qrb = q0 + wave * 16 + lg * 4;
        #pragma unroll
        for (int d = 0; d < 4; ++d) {
            int col = hcol + d * 16 + lr;
            #pragma unroll
            for (int r = 0; r < 4; ++r)
                C[(rowbase + qrb + r) * DMODEL + col] = f2bf(acc_o[d][r] * linv[r]);
        }
    }
}

// ---------------------------------------------------------------------------
extern "C" void kernel_launch(void* const* d_in, const int* in_sizes, int n_in,
                              void* d_out, int out_size, void* d_ws, size_t ws_size,
                              hipStream_t stream)
{
    const float* q  = (const float*)d_in[0];
    const float* k  = (const float*)d_in[1];
    const float* v  = (const float*)d_in[2];
    const float* Wq = (const float*)d_in[3];
    const float* bq = (const float*)d_in[4];
    const float* Wk = (const float*)d_in[5];
    const float* bk = (const float*)d_in[6];
    const float* Wv = (const float*)d_in[7];
    const float* bv = (const float*)d_in[8];
    const float* Wf = (const float*)d_in[9];
    const float* bf = (const float*)d_in[10];

    unsigned short* ws = (unsigned short*)d_ws;
    const size_t SZ = (size_t)MROWS * DMODEL;        // 8388608 elems
    unsigned short* Vt = ws;                         // [0, SZ)   V^T per head
    unsigned short* Cb = ws + SZ;                    // [SZ, 2SZ) attn out
    unsigned short* Kb = ws + 3 * SZ;                // [3SZ,4SZ) K projection

    unsigned short* scr = (unsigned short*)d_out;    // d_out as scratch (16M ushorts)
    unsigned short* WqT = scr;                       // [0,1M)
    unsigned short* WkT = scr + 1048576;             // [1M,2M)
    unsigned short* WvT = scr + 2097152;             // [2M,3M)
    unsigned short* WfT = scr + 3145728;             // [3M,4M)
    unsigned short* Qb  = scr + 4194304;             // [4M,12M)

    const float qscale = 0.02209708691207961f * 1.44269504088896341f;

    // 1. all four weight transposes in one launch
    transpose_cvt4_kernel<<<dim3(16, 16, 4), 256, 0, stream>>>(
        Wq, WqT, Wk, WkT, Wv, WvT, Wf, WfT);

    // 2. Q, K, V projections in ONE z=3 launch, fp32 A with fused convert.
    //    Q pre-scaled into exp2 domain; V written directly in Vt layout.
    {
        GArg gq{q, WqT, bq, Qb, qscale, 0};
        GArg gk{k, WkT, bk, Kb, 1.0f,   0};
        GArg gv{v, WvT, bv, Vt, 1.0f,   3};
        gemm_kernel<true><<<dim3(64, 8, 3), 256, 0, stream>>>(
            gq, gk, gv, MROWS, DMODEL, DMODEL);
    }

    // 3. attention: Qb, Kb, Vt -> Cb
    attn_kernel<<<dim3(BB * NHEAD, 8), 512, 0, stream>>>(Qb, Kb, Vt, Cb);

    // 4. output projection: Cb @ WfT + bf -> d_out fp32 (scratch regions dead)
    {
        GArg gf{Cb, WfT, bf, (float*)d_out, 1.0f, 2};
        gemm_kernel<false><<<dim3(64, 8, 1), 256, 0, stream>>>(
            gf, gf, gf, MROWS, DMODEL, DMODEL);
    }
}